// Round 7
// baseline (69.982 us; speedup 1.0000x reference)
//
#include <hip/hip_runtime.h>
#include <hip/hip_bf16.h>

// B=4, T=4096, E=512, H=64. out fp32 [B,T,H].
#define Bn 4
#define Tn 4096
#define En 512
#define Hn 64
#define NEGINF -3e38f

typedef __attribute__((ext_vector_type(8))) __bf16 bf16x8;
typedef __attribute__((ext_vector_type(4))) __bf16 bf16x4;
typedef __attribute__((ext_vector_type(4))) float f32x4;

#define MFMA16(a, b, c) __builtin_amdgcn_mfma_f32_16x16x32_bf16(a, b, c, 0, 0, 0)

__device__ __forceinline__ unsigned short f2bf(float f) {
    union { float f; unsigned u; } v; v.f = f;
    unsigned r = v.u + 0x7fffu + ((v.u >> 16) & 1u);
    return (unsigned short)(r >> 16);
}

// ---------------- kernel 1: W fp32 -> bf16 concat [192][512] ----------------
__global__ void wcvt(const float* __restrict__ Wq, const float* __restrict__ Wk,
                     const float* __restrict__ Wv, unsigned short* __restrict__ Wo) {
    int i = blockIdx.x * 256 + threadIdx.x;      // 0..98303
    int mat = i >> 15;                            // each W is 64*512 = 32768
    int off = i & 32767;
    const float* s = (mat == 0) ? Wq : ((mat == 1) ? Wk : Wv);
    Wo[i] = f2bf(s[off]);
}

// ---------------- kernel 2: fused QKV projection (bf16 MFMA GEMM) -----------
__launch_bounds__(256, 2)
__global__ void proj(const float* __restrict__ x, const unsigned short* __restrict__ Wo,
                     unsigned short* __restrict__ q16, unsigned short* __restrict__ k16,
                     unsigned short* __restrict__ vt16) {
    __shared__ unsigned short sA[64 * 72];
    __shared__ unsigned short sW[192 * 72];
    const int tid = threadIdx.x;
    const int w = tid >> 6, lane = tid & 63, r = lane & 15, g = lane >> 4;
    const int row0 = blockIdx.x * 64;

    f32x4 acc[12];
#pragma unroll
    for (int i = 0; i < 12; ++i) acc[i] = (f32x4){0.f, 0.f, 0.f, 0.f};

    for (int k0 = 0; k0 < En; k0 += 64) {
#pragma unroll
        for (int i = 0; i < 2; ++i) {
            int c = tid + i * 256; int arow = c >> 3, kc = (c & 7) * 8;
            const float4* xp = (const float4*)&x[(row0 + arow) * En + k0 + kc];
            float4 f0 = xp[0], f1 = xp[1];
            union { bf16x8 v; unsigned short u[8]; } t;
            t.u[0] = f2bf(f0.x); t.u[1] = f2bf(f0.y); t.u[2] = f2bf(f0.z); t.u[3] = f2bf(f0.w);
            t.u[4] = f2bf(f1.x); t.u[5] = f2bf(f1.y); t.u[6] = f2bf(f1.z); t.u[7] = f2bf(f1.w);
            *(bf16x8*)&sA[arow * 72 + kc] = t.v;
        }
#pragma unroll
        for (int i = 0; i < 6; ++i) {
            int c = tid + i * 256; int wrow = c >> 3, kc = (c & 7) * 8;
            bf16x8 wv = *(const bf16x8*)&Wo[wrow * En + k0 + kc];
            *(bf16x8*)&sW[wrow * 72 + kc] = wv;
        }
        __syncthreads();
        bf16x8 a0 = *(bf16x8*)&sA[(w * 16 + r) * 72 + g * 8];
        bf16x8 a1 = *(bf16x8*)&sA[(w * 16 + r) * 72 + 32 + g * 8];
#pragma unroll
        for (int ct = 0; ct < 12; ++ct) {
            bf16x8 b0 = *(bf16x8*)&sW[(ct * 16 + r) * 72 + g * 8];
            bf16x8 b1 = *(bf16x8*)&sW[(ct * 16 + r) * 72 + 32 + g * 8];
            acc[ct] = MFMA16(a0, b0, acc[ct]);
            acc[ct] = MFMA16(a1, b1, acc[ct]);
        }
        __syncthreads();
    }
#pragma unroll
    for (int ct = 0; ct < 12; ++ct) {
        int n = ct * 16 + r;
#pragma unroll
        for (int reg = 0; reg < 4; ++reg) {
            int gr = row0 + w * 16 + g * 4 + reg;
            unsigned short bv = f2bf(acc[ct][reg]);
            if (n < 64) {
                q16[gr * 64 + n] = bv;
            } else if (n < 128) {
                k16[gr * 64 + (n - 64)] = bv;
            } else {
                int h = n - 128; int bb = gr >> 12; int t = gr & 4095;
                vt16[((bb * 64 + h) << 12) + t] = bv;
            }
        }
    }
}

// ---------------- kernel 3: causal flash attention (fat tiles) ---------------
// 256 blocks x 512 thr. Block = one 64-row q-tile (j = 63-(bid>>2), b = bid&3
// -> one batch per XCD, K/V L2-resident). 1 block/CU. KV tile 256, dbuf
// 2 x (K 32KB + V^T 32KB) = 128KB; merge oM (64KB) overlaid post-loop.
// Waves: 2 sq x 4 sk; each wave: 32 q (2 qf) x 64 kv (4 ct) per iter ->
// 32 MFMA per softmax pass; K/V LDS reads shared across qf.
__launch_bounds__(512, 2)
__global__ void attn(const unsigned short* __restrict__ q16, const unsigned short* __restrict__ k16,
                     const unsigned short* __restrict__ vt16, float* __restrict__ out) {
    __shared__ __align__(16) unsigned char lds[2][65536];  // [buf][K 32KB | V 32KB]
    __shared__ float mM[2][4][32], lM[2][4][32];
    float* const oMp = (float*)&lds[0][0];                 // overlay [2sq][4sk][32][64] f32

    const int tid = threadIdx.x;
    const int w = tid >> 6, lane = tid & 63, r = lane & 15, g = lane >> 4;
    const int sq = w >> 2, sk = w & 3;
    const int bid = blockIdx.x;
    const int b = bid & 3;                                 // batch per XCD
    const int jt = 63 - (bid >> 2);                        // longest first
    const size_t kbase = (size_t)b * Tn;
    const float scale = 0.125f;

    const int q0 = jt * 64;
    const int nIt = (64 * jt + 319) >> 8;                  // ceil(64(jt+1)/256)
    const int qrow = b * Tn + q0 + sq * 32;
    const int qminw = q0 + sq * 32;
    const int qmaxw = qminw + 31;

    bf16x8 bq[2][2];
#pragma unroll
    for (int qf = 0; qf < 2; ++qf)
#pragma unroll
        for (int hh = 0; hh < 2; ++hh)
            bq[qf][hh] = *(const bf16x8*)&q16[(qrow + qf * 16 + r) * 64 + hh * 32 + g * 8];

    f32x4 o[2][4];
#pragma unroll
    for (int qf = 0; qf < 2; ++qf)
#pragma unroll
        for (int i = 0; i < 4; ++i) o[qf][i] = (f32x4){0.f, 0.f, 0.f, 0.f};
    float m_[2] = {-1e30f, -1e30f}, l_[2] = {0.f, 0.f};

    // prologue: stage kv tile 0 into buf 0
    {
#pragma unroll
        for (int p = 0; p < 4; ++p) {
            int row = p * 64 + (tid >> 3), cb = (tid & 7) * 16;
            bf16x8 t = *(const bf16x8*)((const char*)k16 + (kbase + row) * 128 + cb);
            *(bf16x8*)&lds[0][row * 128 + (cb ^ ((row & 7) << 4))] = t;
        }
#pragma unroll
        for (int p = 0; p < 4; ++p) {
            int h = p * 16 + (tid >> 5), cb = (tid & 31) * 16;
            bf16x8 t = *(const bf16x8*)((const char*)vt16 + ((size_t)(b * 64 + h)) * 8192 + cb);
            *(bf16x8*)&lds[0][32768 + h * 512 + (cb ^ ((h & 7) << 4))] = t;
        }
    }
    __syncthreads();

    for (int it = 0; it < nIt; ++it) {
        const int pp = it & 1;
        const int kv0 = it * 256;
        const bool more = (it + 1 < nIt);
        // T14: issue next-tile global loads early
        bf16x8 st[8];
        int sd[8];
        if (more) {
            int nkv = kv0 + 256;
#pragma unroll
            for (int p = 0; p < 4; ++p) {
                int row = p * 64 + (tid >> 3), cb = (tid & 7) * 16;
                st[p] = *(const bf16x8*)((const char*)k16 + (kbase + nkv + row) * 128 + cb);
                sd[p] = row * 128 + (cb ^ ((row & 7) << 4));
            }
#pragma unroll
            for (int p = 0; p < 4; ++p) {
                int h = p * 16 + (tid >> 5), cb = (tid & 31) * 16;
                st[4 + p] = *(const bf16x8*)((const char*)vt16 + ((size_t)(b * 64 + h)) * 8192 + (size_t)nkv * 2 + cb);
                sd[4 + p] = 32768 + h * 512 + (cb ^ ((h & 7) << 4));
            }
        }
        // compute on buf pp (wave-uniform causal skip)
        if (kv0 + sk * 64 <= qmaxw) {
            const unsigned char* K = &lds[pp][0];
            const unsigned char* V = &lds[pp][32768];
            f32x4 s[2][4];
            __builtin_amdgcn_s_setprio(1);
#pragma unroll
            for (int ct = 0; ct < 4; ++ct) {
                int row = sk * 64 + ct * 16 + r;
                int base = row * 128, sw = (row & 7) << 4;
                bf16x8 ak0 = *(const bf16x8*)&K[base + ((g * 16) ^ sw)];
                bf16x8 ak1 = *(const bf16x8*)&K[base + ((64 + g * 16) ^ sw)];
#pragma unroll
                for (int qf = 0; qf < 2; ++qf) {
                    f32x4 t = (f32x4){0.f, 0.f, 0.f, 0.f};
                    t = MFMA16(ak0, bq[qf][0], t);
                    t = MFMA16(ak1, bq[qf][1], t);
                    s[qf][ct] = t;
                }
            }
            __builtin_amdgcn_s_setprio(0);
            // mask + scale
            if (kv0 + sk * 64 + 63 > qminw) {
#pragma unroll
                for (int qf = 0; qf < 2; ++qf) {
                    int qq = qminw + qf * 16 + r;
#pragma unroll
                    for (int ct = 0; ct < 4; ++ct)
#pragma unroll
                        for (int reg = 0; reg < 4; ++reg) {
                            int kv = kv0 + sk * 64 + ct * 16 + g * 4 + reg;
                            s[qf][ct][reg] = (kv > qq) ? NEGINF : s[qf][ct][reg] * scale;
                        }
                }
            } else {
#pragma unroll
                for (int qf = 0; qf < 2; ++qf)
#pragma unroll
                    for (int ct = 0; ct < 4; ++ct)
#pragma unroll
                        for (int reg = 0; reg < 4; ++reg) s[qf][ct][reg] *= scale;
            }
            // per-qf window max (in-lane 16-tree + 2 shuffles)
            float mx[2];
#pragma unroll
            for (int qf = 0; qf < 2; ++qf) {
                float a0 = fmaxf(fmaxf(s[qf][0][0], s[qf][0][1]), fmaxf(s[qf][0][2], s[qf][0][3]));
                float a1 = fmaxf(fmaxf(s[qf][1][0], s[qf][1][1]), fmaxf(s[qf][1][2], s[qf][1][3]));
                float a2 = fmaxf(fmaxf(s[qf][2][0], s[qf][2][1]), fmaxf(s[qf][2][2], s[qf][2][3]));
                float a3 = fmaxf(fmaxf(s[qf][3][0], s[qf][3][1]), fmaxf(s[qf][3][2], s[qf][3][3]));
                float mxv = fmaxf(fmaxf(a0, a1), fmaxf(a2, a3));
                mxv = fmaxf(mxv, __shfl_xor(mxv, 16));
                mxv = fmaxf(mxv, __shfl_xor(mxv, 32));
                mx[qf] = mxv;
            }
            // defer-max rescale
            bool need = (mx[0] > m_[0] + 8.0f) || (mx[1] > m_[1] + 8.0f);
            if (__any(need)) {
#pragma unroll
                for (int qf = 0; qf < 2; ++qf) {
                    float mn = fmaxf(m_[qf], mx[qf]);
                    float corr = __expf(m_[qf] - mn);
                    m_[qf] = mn;
                    l_[qf] *= corr;
                    float cq[4];
#pragma unroll
                    for (int reg = 0; reg < 4; ++reg) cq[reg] = __shfl(corr, g * 4 + reg);
#pragma unroll
                    for (int cth = 0; cth < 4; ++cth)
#pragma unroll
                        for (int reg = 0; reg < 4; ++reg) o[qf][cth][reg] *= cq[reg];
                }
            }
            // exp + sum
#pragma unroll
            for (int qf = 0; qf < 2; ++qf) {
#pragma unroll
                for (int ct = 0; ct < 4; ++ct)
#pragma unroll
                    for (int reg = 0; reg < 4; ++reg)
                        s[qf][ct][reg] = __expf(s[qf][ct][reg] - m_[qf]);
                float b0s = (s[qf][0][0] + s[qf][0][1]) + (s[qf][0][2] + s[qf][0][3]);
                float b1s = (s[qf][1][0] + s[qf][1][1]) + (s[qf][1][2] + s[qf][1][3]);
                float b2s = (s[qf][2][0] + s[qf][2][1]) + (s[qf][2][2] + s[qf][2][3]);
                float b3s = (s[qf][3][0] + s[qf][3][1]) + (s[qf][3][2] + s[qf][3][3]);
                float sm = (b0s + b1s) + (b2s + b3s);
                sm += __shfl_xor(sm, 16);
                sm += __shfl_xor(sm, 32);
                l_[qf] += sm;
            }
            // pack P: frag kf slot j <- s[kf*2 + (j>>2)][j&3]
            union { bf16x8 v; unsigned short u[8]; } pk[2][2];
#pragma unroll
            for (int qf = 0; qf < 2; ++qf)
#pragma unroll
                for (int kf = 0; kf < 2; ++kf)
#pragma unroll
                    for (int jj = 0; jj < 4; ++jj) {
                        pk[qf][kf].u[jj] = f2bf(s[qf][kf * 2][jj]);
                        pk[qf][kf].u[4 + jj] = f2bf(s[qf][kf * 2 + 1][jj]);
                    }
            // PV: V B-frags shared across qf
            __builtin_amdgcn_s_setprio(1);
#pragma unroll
            for (int cth = 0; cth < 4; ++cth) {
                int h = cth * 16 + r;
                int vb = h * 512, sw2 = (h & 7) << 4;
#pragma unroll
                for (int kf = 0; kf < 2; ++kf) {
                    int off = sk * 128 + kf * 64 + g * 8;
                    union { bf16x8 v; bf16x4 h4[2]; } vv;
                    vv.h4[0] = *(const bf16x4*)&V[vb + (off ^ sw2)];
                    vv.h4[1] = *(const bf16x4*)&V[vb + ((off + 32) ^ sw2)];
                    o[0][cth] = MFMA16(pk[0][kf].v, vv.v, o[0][cth]);
                    o[1][cth] = MFMA16(pk[1][kf].v, vv.v, o[1][cth]);
                }
            }
            __builtin_amdgcn_s_setprio(0);
        }
        if (more) {
            unsigned char* D = &lds[pp ^ 1][0];
#pragma unroll
            for (int p = 0; p < 8; ++p) *(bf16x8*)&D[sd[p]] = st[p];
        }
        __syncthreads();
    }

    // ---- partials to LDS (oM overlays stage buffers; loop done) ----
#pragma unroll
    for (int qf = 0; qf < 2; ++qf)
#pragma unroll
        for (int cth = 0; cth < 4; ++cth)
#pragma unroll
            for (int reg = 0; reg < 4; ++reg)
                oMp[(((sq * 4 + sk) * 32) + qf * 16 + g * 4 + reg) * 64 + cth * 16 + r] = o[qf][cth][reg];
    if (lane < 16) {
        mM[sq][sk][lane] = m_[0];
        mM[sq][sk][16 + lane] = m_[1];
        lM[sq][sk][lane] = l_[0];
        lM[sq][sk][16 + lane] = l_[1];
    }
    __syncthreads();

    // ---- merge 4-way across sk; wave (sq,sk) takes rows sk*8 + (lane>>3) ----
    {
        int rr = sk * 8 + (lane >> 3);
        int coff = (lane & 7) * 8;
        float m0 = mM[sq][0][rr], m1 = mM[sq][1][rr], m2 = mM[sq][2][rr], m3 = mM[sq][3][rr];
        float M = fmaxf(fmaxf(m0, m1), fmaxf(m2, m3));
        float w0 = __expf(m0 - M), w1 = __expf(m1 - M), w2 = __expf(m2 - M), w3 = __expf(m3 - M);
        float L = w0 * lM[sq][0][rr] + w1 * lM[sq][1][rr] + w2 * lM[sq][2][rr] + w3 * lM[sq][3][rr];
        float inv = 1.0f / L;
        int orow = b * Tn + q0 + sq * 32 + rr;
        float acc[8];
#pragma unroll
        for (int jj = 0; jj < 8; ++jj) {
            int col = coff + jj;
            acc[jj] = (w0 * oMp[((sq * 4 + 0) * 32 + rr) * 64 + col] +
                       w1 * oMp[((sq * 4 + 1) * 32 + rr) * 64 + col] +
                       w2 * oMp[((sq * 4 + 2) * 32 + rr) * 64 + col] +
                       w3 * oMp[((sq * 4 + 3) * 32 + rr) * 64 + col]) * inv;
        }
        float4* op = (float4*)&out[orow * 64 + coff];
        op[0] = (float4){acc[0], acc[1], acc[2], acc[3]};
        op[1] = (float4){acc[4], acc[5], acc[6], acc[7]};
    }
}

extern "C" void kernel_launch(void* const* d_in, const int* in_sizes, int n_in,
                              void* d_out, int out_size, void* d_ws, size_t ws_size,
                              hipStream_t stream) {
    const float* x  = (const float*)d_in[0];
    const float* Wq = (const float*)d_in[1];
    const float* Wk = (const float*)d_in[2];
    const float* Wv = (const float*)d_in[3];
    float* out = (float*)d_out;
    char* ws = (char*)d_ws;

    unsigned short* Wo  = (unsigned short*)ws;                       // 192*512*2   = 196608 B
    unsigned short* q16 = (unsigned short*)(ws + 196608);            // 16384*64*2  = 2 MiB
    unsigned short* k16 = (unsigned short*)(ws + 196608 + 2097152);
    unsigned short* v16 = (unsigned short*)(ws + 196608 + 2 * 2097152);

    hipLaunchKernelGGL(wcvt, dim3(384), dim3(256), 0, stream, Wq, Wk, Wv, Wo);
    hipLaunchKernelGGL(proj, dim3(256), dim3(256), 0, stream, x, Wo, q16, k16, v16);
    hipLaunchKernelGGL(attn, dim3(256), dim3(512), 0, stream, q16, k16, v16, out);
}